// Round 13
// baseline (229.912 us; speedup 1.0000x reference)
//
#include <hip/hip_runtime.h>
#include <hip/hip_bf16.h>

// Problem constants
#define Wd    96
#define Hd    96
#define HW    9216           // 96*96
#define Bn    4
#define Cn    64             // channels per section
#define C3    192            // 3*Cn
#define On    64             // out channels
#define NPIX  (Bn*HW)        // 36864
#define NFEAT (Bn*Cn*HW)     // 2359296 elements per output tensor
#define NWTB  (9*6*4*512)    // 110592 bf16 frag-linear deform weights
#define NWTB2 (18*2*64*8)    // 18432 bf16 frag-linear offset weights

typedef __attribute__((ext_vector_type(8))) short s8v;    // 8 bf16
typedef __attribute__((ext_vector_type(4))) unsigned int u4v;
typedef __attribute__((ext_vector_type(4))) float f4v;    // MFMA accum
typedef __hip_bfloat16 bf16;

__device__ __forceinline__ short f2bfs(float x) {
    return __builtin_bit_cast(short, __float2bfloat16(x));
}
__device__ __forceinline__ float blo(unsigned u) {
    return __builtin_bit_cast(float, u << 16);
}
__device__ __forceinline__ float bhi(unsigned u) {
    return __builtin_bit_cast(float, u & 0xffff0000u);
}
__device__ __forceinline__ unsigned packbf2(float lo, float hi) {
    unsigned a = (unsigned)(unsigned short)f2bfs(lo);
    unsigned b = (unsigned)(unsigned short)f2bfs(hi);
    return a | (b << 16);
}

// ===========================================================================
// repack: NCHW ref/dist -> bf16 NHWC packed[b][p][c] (c = ref|dist|diff),
// fused diff; diff (NCHW f32) to d_out second half.
// ===========================================================================
__global__ __launch_bounds__(256) void repack_kernel(
        const float* __restrict__ ref,
        const float* __restrict__ dist,
        unsigned int* __restrict__ packed,    // [NPIX][96] bf16-pairs
        float* __restrict__ out_diff) {
    __shared__ float lds[64][193];            // 49408 B

    int tid = threadIdx.x;
    int lane = tid & 63;
    int wv = tid >> 6;
    int blk = blockIdx.x;
    int b = blk / (HW / 64);
    int p0 = (blk % (HW / 64)) * 64;

    for (int cc = 0; cc < 16; ++cc) {
        int ch = wv * 16 + cc;
        size_t g = ((size_t)(b * Cn + ch)) * HW + p0 + lane;
        float r = ref[g];
        float d = dist[g];
        float q = (r - d) * (r - d);
        lds[lane][ch] = r;
        lds[lane][Cn + ch] = d;
        lds[lane][2 * Cn + ch] = q;
        out_diff[g] = q;
    }
    __syncthreads();

    for (int i = tid; i < 64 * 96; i += 256) {
        int p = i / 96;
        int cp = i % 96;
        packed[((size_t)(b * HW) + p0 + p) * 96 + cp] =
            packbf2(lds[p][2 * cp], lds[p][2 * cp + 1]);
    }
}

// ---------------------------------------------------------------------------
// wts_kernel: both weight repacks in one launch (frag-linear bf16).
// ---------------------------------------------------------------------------
__global__ void wts_kernel(const float* __restrict__ dw,
                           const float* __restrict__ ow,
                           bf16* __restrict__ wtb,
                           bf16* __restrict__ wtb2) {
    int e = blockIdx.x * blockDim.x + threadIdx.x;
    if (e < NWTB) {
        int j = e & 7;
        int L = (e >> 3) & 63;
        int mt = (e >> 9) & 3;
        int rest = e >> 11;
        int kc = rest % 6;
        int tap = rest / 6;
        int o = mt * 16 + (L & 15);
        int c = kc * 32 + (L >> 4) * 8 + j;
        wtb[e] = __float2bfloat16(dw[((size_t)o * C3 + c) * 9 + tap]);
    } else if (e < NWTB + NWTB2) {
        int e2 = e - NWTB;
        int j = e2 & 7;
        int L = (e2 >> 3) & 63;
        int mt = (e2 >> 9) & 1;
        int kc2 = e2 >> 10;           // 0..17 = t*2+kc
        int v = mt * 16 + (L & 15);
        int k = kc2 * 32 + ((L >> 4) & 3) * 8 + j;
        int c = k & 63;
        int tap = k >> 6;
        float val = (v < 18) ? ow[((size_t)v * Cn + c) * 9 + tap] : 0.f;
        wtb2[e2] = __float2bfloat16(val);
    }
}

// ===========================================================================
// fused_mfma: ONE wave per block handles 64 px.
// Phase 0: offset conv (M=v 32, N=16 px x 4 tiles, K=576) -> offsets in LDS.
// Phase 1: deform conv (M=o 64, N=16 px x 4 tiles, K=1728): per (t,kc) the
//   4 weight frags are loaded ONCE and reused across 4 px-tiles (weight
//   L2 transactions /4 vs R11); 16 independent gathers per kc give ILP.
// __launch_bounds__(64,1): VGPR budget 512 so acc[4][4]+g[4][4] never spill.
// ===========================================================================
struct Ctx {
    int o00, o01, o10, o11;
    float W00, W01, W10, W11;
};

__device__ __forceinline__ Ctx mkctx(int t, int y, int x, float2 o2) {
    Ctx c;
    float py = (float)(y - 1 + t / 3) + o2.x;
    float pxs = (float)(x - 1 + t % 3) + o2.y;
    float fy = floorf(py), fx = floorf(pxs);
    int y0 = (int)fy, x0 = (int)fx;
    int y1 = y0 + 1, x1 = x0 + 1;
    float ay = py - fy, ax = pxs - fx;
    bool vy0 = (unsigned)y0 < (unsigned)Hd;
    bool vy1 = (unsigned)y1 < (unsigned)Hd;
    bool vx0 = (unsigned)x0 < (unsigned)Wd;
    bool vx1 = (unsigned)x1 < (unsigned)Wd;
    c.W00 = (vy0 && vx0) ? (1.f - ay) * (1.f - ax) : 0.f;
    c.W01 = (vy0 && vx1) ? (1.f - ay) * ax : 0.f;
    c.W10 = (vy1 && vx0) ? ay * (1.f - ax) : 0.f;
    c.W11 = (vy1 && vx1) ? ay * ax : 0.f;
    int y0c = min(max(y0, 0), Hd - 1), y1c = min(max(y1, 0), Hd - 1);
    int x0c = min(max(x0, 0), Wd - 1), x1c = min(max(x1, 0), Wd - 1);
    c.o00 = (y0c * Wd + x0c) * (C3 * 2);
    c.o01 = (y0c * Wd + x1c) * (C3 * 2);
    c.o10 = (y1c * Wd + x0c) * (C3 * 2);
    c.o11 = (y1c * Wd + x1c) * (C3 * 2);
    return c;
}

__global__ __launch_bounds__(64, 1) void fused_mfma(
        const bf16* __restrict__ packed,
        const bf16* __restrict__ wtb,
        const bf16* __restrict__ wtb2,
        const float* __restrict__ ob,
        const float* __restrict__ db,
        float* __restrict__ out) {
    __shared__ float offl[64][20];            // 5120 B, even pitch (b64 align)

    int L = threadIdx.x;
    int px = L & 15;
    int lg = L >> 4;
    int blk = blockIdx.x;
    int region = (blk & 7) * 72 + (blk >> 3); // 576 blocks, XCD swizzle
    int p0 = region * 64;
    int b = p0 / HW;
    int pb = p0 - b * HW;
    const char* pkb = (const char*)packed + (size_t)b * HW * (C3 * 2);

    int xs[4], ys[4];
#pragma unroll
    for (int pt = 0; pt < 4; ++pt) {
        int pid = pb + pt * 16 + px;
        xs[pt] = pid % Wd;
        ys[pt] = pid / Wd;
    }

    // ================= phase 0: offset conv =================
    {
        const s8v* A2 = (const s8v*)wtb2;
        f4v oa0[4], oa1[4];
#pragma unroll
        for (int pt = 0; pt < 4; ++pt) {
            oa0[pt] = (f4v){0.f, 0.f, 0.f, 0.f};
            oa1[pt] = (f4v){0.f, 0.f, 0.f, 0.f};
        }
        s8v orw[2][4][2];
        short omk[2][4];
#pragma unroll
        for (int pt = 0; pt < 4; ++pt) {      // prologue: tap 0
            int yy = ys[pt] - 1, xx = xs[pt] - 1;
            bool val = (unsigned)yy < (unsigned)Hd && (unsigned)xx < (unsigned)Wd;
            int oc = ((val ? yy : 0) * Wd + (val ? xx : 0)) * (C3 * 2);
            omk[0][pt] = val ? (short)-1 : (short)0;
            orw[0][pt][0] = *(const s8v*)(pkb + oc + (0 * 4 + lg) * 16);
            orw[0][pt][1] = *(const s8v*)(pkb + oc + (1 * 4 + lg) * 16);
        }
#pragma unroll
        for (int t = 0; t < 9; ++t) {
            if (t < 8) {
                int tn = t + 1;
#pragma unroll
                for (int pt = 0; pt < 4; ++pt) {
                    int yy = ys[pt] - 1 + tn / 3, xx = xs[pt] - 1 + tn % 3;
                    bool val = (unsigned)yy < (unsigned)Hd && (unsigned)xx < (unsigned)Wd;
                    int oc = ((val ? yy : 0) * Wd + (val ? xx : 0)) * (C3 * 2);
                    omk[tn & 1][pt] = val ? (short)-1 : (short)0;
                    orw[tn & 1][pt][0] = *(const s8v*)(pkb + oc + (0 * 4 + lg) * 16);
                    orw[tn & 1][pt][1] = *(const s8v*)(pkb + oc + (1 * 4 + lg) * 16);
                }
            }
#pragma unroll
            for (int kc = 0; kc < 2; ++kc) {
                s8v a0 = A2[((t * 2 + kc) * 2 + 0) * 64 + L];
                s8v a1 = A2[((t * 2 + kc) * 2 + 1) * 64 + L];
#pragma unroll
                for (int pt = 0; pt < 4; ++pt) {
                    s8v bfrag = orw[t & 1][pt][kc] & omk[t & 1][pt];
                    oa0[pt] = __builtin_amdgcn_mfma_f32_16x16x32_bf16(a0, bfrag, oa0[pt], 0, 0, 0);
                    oa1[pt] = __builtin_amdgcn_mfma_f32_16x16x32_bf16(a1, bfrag, oa1[pt], 0, 0, 0);
                }
            }
        }
        // offsets + bias -> LDS[pixel][v]
        float ob0[4];
#pragma unroll
        for (int r = 0; r < 4; ++r) ob0[r] = ob[lg * 4 + r];
#pragma unroll
        for (int pt = 0; pt < 4; ++pt)
#pragma unroll
            for (int r = 0; r < 4; ++r)
                offl[pt * 16 + px][lg * 4 + r] = oa0[pt][r] + ob0[r];
        if (lg == 0) {
#pragma unroll
            for (int r = 0; r < 2; ++r) {
                float obx = ob[16 + r];
#pragma unroll
                for (int pt = 0; pt < 4; ++pt)
                    offl[pt * 16 + px][16 + r] = oa1[pt][r] + obx;
            }
        }
    }
    __syncthreads();

    // ================= phase 1: deform conv =================
    const s8v* A1 = (const s8v*)wtb;
    f4v acc[4][4];
#pragma unroll
    for (int pt = 0; pt < 4; ++pt)
#pragma unroll
        for (int mt = 0; mt < 4; ++mt)
            acc[pt][mt] = (f4v){0.f, 0.f, 0.f, 0.f};

#pragma unroll 1
    for (int t = 0; t < 9; ++t) {
        Ctx c[4];
#pragma unroll
        for (int pt = 0; pt < 4; ++pt) {
            float2 o2 = *(const float2*)&offl[pt * 16 + px][2 * t];
            c[pt] = mkctx(t, ys[pt], xs[pt], o2);
        }
#pragma unroll
        for (int kc = 0; kc < 6; ++kc) {
            s8v w0 = A1[((t * 6 + kc) * 4 + 0) * 64 + L];
            s8v w1 = A1[((t * 6 + kc) * 4 + 1) * 64 + L];
            s8v w2 = A1[((t * 6 + kc) * 4 + 2) * 64 + L];
            s8v w3 = A1[((t * 6 + kc) * 4 + 3) * 64 + L];
            s8v g[4][4];
            int co = (kc * 4 + lg) * 16;
#pragma unroll
            for (int pt = 0; pt < 4; ++pt) {
                g[pt][0] = *(const s8v*)(pkb + c[pt].o00 + co);
                g[pt][1] = *(const s8v*)(pkb + c[pt].o01 + co);
                g[pt][2] = *(const s8v*)(pkb + c[pt].o10 + co);
                g[pt][3] = *(const s8v*)(pkb + c[pt].o11 + co);
            }
#pragma unroll
            for (int pt = 0; pt < 4; ++pt) {
                u4v u00 = __builtin_bit_cast(u4v, g[pt][0]);
                u4v u01 = __builtin_bit_cast(u4v, g[pt][1]);
                u4v u10 = __builtin_bit_cast(u4v, g[pt][2]);
                u4v u11 = __builtin_bit_cast(u4v, g[pt][3]);
                const Ctx cc = c[pt];
                u4v bu;
#pragma unroll
                for (int p = 0; p < 4; ++p) {
                    float vlo = cc.W00 * blo(u00[p]) + cc.W01 * blo(u01[p])
                              + cc.W10 * blo(u10[p]) + cc.W11 * blo(u11[p]);
                    float vhi = cc.W00 * bhi(u00[p]) + cc.W01 * bhi(u01[p])
                              + cc.W10 * bhi(u10[p]) + cc.W11 * bhi(u11[p]);
                    bu[p] = packbf2(vlo, vhi);
                }
                s8v bfrag = __builtin_bit_cast(s8v, bu);
                acc[pt][0] = __builtin_amdgcn_mfma_f32_16x16x32_bf16(w0, bfrag, acc[pt][0], 0, 0, 0);
                acc[pt][1] = __builtin_amdgcn_mfma_f32_16x16x32_bf16(w1, bfrag, acc[pt][1], 0, 0, 0);
                acc[pt][2] = __builtin_amdgcn_mfma_f32_16x16x32_bf16(w2, bfrag, acc[pt][2], 0, 0, 0);
                acc[pt][3] = __builtin_amdgcn_mfma_f32_16x16x32_bf16(w3, bfrag, acc[pt][3], 0, 0, 0);
            }
        }
    }

    // epilogue: bias + ReLU, D col = px, row(o in tile) = lg*4+r
#pragma unroll
    for (int mt = 0; mt < 4; ++mt) {
#pragma unroll
        for (int r = 0; r < 4; ++r) {
            int o = mt * 16 + lg * 4 + r;
            float bi = db[o];
            float* op = out + ((size_t)(b * On + o)) * HW + pb + px;
#pragma unroll
            for (int pt = 0; pt < 4; ++pt)
                op[pt * 16] = fmaxf(acc[pt][mt][r] + bi, 0.f);
        }
    }
}

// ---------------------------------------------------------------------------
extern "C" void kernel_launch(void* const* d_in, const int* in_sizes, int n_in,
                              void* d_out, int out_size, void* d_ws, size_t ws_size,
                              hipStream_t stream) {
    const float* ref  = (const float*)d_in[0];
    const float* dist = (const float*)d_in[1];
    const float* ow   = (const float*)d_in[2];
    const float* ob   = (const float*)d_in[3];
    const float* dw   = (const float*)d_in[4];
    const float* db   = (const float*)d_in[5];

    float* out = (float*)d_out;               // [feat | diff], each NFEAT f32

    // ws: wtb bf16 | wtb2 bf16 | packed bf16 [NPIX][192]
    bf16* ws_wtb  = (bf16*)d_ws;
    bf16* ws_wtb2 = ws_wtb + NWTB;
    bf16* ws_pk   = ws_wtb2 + NWTB2;

    repack_kernel<<<Bn * (HW / 64), 256, 0, stream>>>(
        ref, dist, (unsigned int*)ws_pk, out + NFEAT);
    wts_kernel<<<(NWTB + NWTB2 + 255) / 256, 256, 0, stream>>>(
        dw, ow, ws_wtb, ws_wtb2);
    fused_mfma<<<NPIX / 64, 64, 0, stream>>>(
        ws_pk, ws_wtb, ws_wtb2, ob, db, out);
}

// Round 14
// 169.858 us; speedup vs baseline: 1.3536x; 1.3536x over previous
//
#include <hip/hip_runtime.h>
#include <hip/hip_bf16.h>

// Problem constants
#define Wd    96
#define Hd    96
#define HW    9216           // 96*96
#define Bn    4
#define Cn    64             // channels per section
#define C3    192            // 3*Cn
#define On    64             // out channels
#define NPIX  (Bn*HW)        // 36864
#define NFEAT (Bn*Cn*HW)     // 2359296 elements per output tensor
#define NWTB  (9*6*4*512)    // 110592 bf16 frag-linear deform weights
#define NWTB2 (18*2*64*8)    // 18432 bf16 frag-linear offset weights
#define WTAP  12288          // shorts per deform tap (6*4*64*8)

typedef __attribute__((ext_vector_type(8))) short s8v;    // 8 bf16
typedef __attribute__((ext_vector_type(4))) unsigned int u4v;
typedef __attribute__((ext_vector_type(4))) float f4v;    // MFMA accum
typedef __hip_bfloat16 bf16;

__device__ __forceinline__ short f2bfs(float x) {
    return __builtin_bit_cast(short, __float2bfloat16(x));
}
__device__ __forceinline__ float blo(unsigned u) {
    return __builtin_bit_cast(float, u << 16);
}
__device__ __forceinline__ float bhi(unsigned u) {
    return __builtin_bit_cast(float, u & 0xffff0000u);
}
__device__ __forceinline__ unsigned packbf2(float lo, float hi) {
    unsigned a = (unsigned)(unsigned short)f2bfs(lo);
    unsigned b = (unsigned)(unsigned short)f2bfs(hi);
    return a | (b << 16);
}

// ===========================================================================
// repack: NCHW ref/dist -> bf16 NHWC packed[b][p][c] (c = ref|dist|diff),
// fused diff; diff (NCHW f32) to d_out second half. ALSO does both weight
// repacks (e = blk*256+tid covers NWTB+NWTB2 = 129024 < 147456 threads).
// ===========================================================================
__global__ __launch_bounds__(256) void repack_kernel(
        const float* __restrict__ ref,
        const float* __restrict__ dist,
        unsigned int* __restrict__ packed,    // [NPIX][96] bf16-pairs
        float* __restrict__ out_diff,
        const float* __restrict__ dw,
        const float* __restrict__ ow,
        bf16* __restrict__ wtb,
        bf16* __restrict__ wtb2) {
    __shared__ float lds[64][193];            // 49408 B

    int tid = threadIdx.x;
    int lane = tid & 63;
    int wv = tid >> 6;
    int blk = blockIdx.x;
    int b = blk / (HW / 64);
    int p0 = (blk % (HW / 64)) * 64;

    // ---- weight repack (independent work, rides along) ----
    {
        int e = blk * 256 + tid;
        if (e < NWTB) {
            int j = e & 7;
            int L = (e >> 3) & 63;
            int mt = (e >> 9) & 3;
            int rest = e >> 11;
            int kc = rest % 6;
            int tap = rest / 6;
            int o = mt * 16 + (L & 15);
            int c = kc * 32 + (L >> 4) * 8 + j;
            wtb[e] = __float2bfloat16(dw[((size_t)o * C3 + c) * 9 + tap]);
        } else if (e < NWTB + NWTB2) {
            int e2 = e - NWTB;
            int j = e2 & 7;
            int L = (e2 >> 3) & 63;
            int mt = (e2 >> 9) & 1;
            int kc2 = e2 >> 10;           // 0..17 = t*2+kc
            int v = mt * 16 + (L & 15);
            int k = kc2 * 32 + ((L >> 4) & 3) * 8 + j;
            int c = k & 63;
            int tap = k >> 6;
            float val = (v < 18) ? ow[((size_t)v * Cn + c) * 9 + tap] : 0.f;
            wtb2[e2] = __float2bfloat16(val);
        }
    }

    for (int cc = 0; cc < 16; ++cc) {
        int ch = wv * 16 + cc;
        size_t g = ((size_t)(b * Cn + ch)) * HW + p0 + lane;
        float r = ref[g];
        float d = dist[g];
        float q = (r - d) * (r - d);
        lds[lane][ch] = r;
        lds[lane][Cn + ch] = d;
        lds[lane][2 * Cn + ch] = q;
        out_diff[g] = q;
    }
    __syncthreads();

    for (int i = tid; i < 64 * 96; i += 256) {
        int p = i / 96;
        int cp = i % 96;
        packed[((size_t)(b * HW) + p0 + p) * 96 + cp] =
            packbf2(lds[p][2 * cp], lds[p][2 * cp + 1]);
    }
}

// ===========================================================================
// fused_mfma: block = 256 thr / 4 waves / 64 px (16 px per wave).
// Phase 0: offset conv (K=576), A-frags from LDS-staged wtb2 -> offl LDS.
// Phase 1: deform conv (K=1728) tap-by-tap; tap weights (24 KB) staged into
//   double-buffered LDS shared by the 4 waves (weight L2 traffic /4 vs R10);
//   staging global loads issued before compute, ds_write after, 1 barrier/tap.
// Gathers stay register-direct in B-frag layout (R9 structure).
// LDS: 48 KB wbuf + 5 KB offl = 54272 B -> <=3 blocks/CU; grid 576x4 waves.
// ===========================================================================
struct Ctx {
    int o00, o01, o10, o11;
    float W00, W01, W10, W11;
};

__device__ __forceinline__ Ctx mkctx(int t, int y, int x, float2 o2) {
    Ctx c;
    float py = (float)(y - 1 + t / 3) + o2.x;
    float pxs = (float)(x - 1 + t % 3) + o2.y;
    float fy = floorf(py), fx = floorf(pxs);
    int y0 = (int)fy, x0 = (int)fx;
    int y1 = y0 + 1, x1 = x0 + 1;
    float ay = py - fy, ax = pxs - fx;
    bool vy0 = (unsigned)y0 < (unsigned)Hd;
    bool vy1 = (unsigned)y1 < (unsigned)Hd;
    bool vx0 = (unsigned)x0 < (unsigned)Wd;
    bool vx1 = (unsigned)x1 < (unsigned)Wd;
    c.W00 = (vy0 && vx0) ? (1.f - ay) * (1.f - ax) : 0.f;
    c.W01 = (vy0 && vx1) ? (1.f - ay) * ax : 0.f;
    c.W10 = (vy1 && vx0) ? ay * (1.f - ax) : 0.f;
    c.W11 = (vy1 && vx1) ? ay * ax : 0.f;
    int y0c = min(max(y0, 0), Hd - 1), y1c = min(max(y1, 0), Hd - 1);
    int x0c = min(max(x0, 0), Wd - 1), x1c = min(max(x1, 0), Wd - 1);
    c.o00 = (y0c * Wd + x0c) * (C3 * 2);
    c.o01 = (y0c * Wd + x1c) * (C3 * 2);
    c.o10 = (y1c * Wd + x0c) * (C3 * 2);
    c.o11 = (y1c * Wd + x1c) * (C3 * 2);
    return c;
}

__global__ __launch_bounds__(256, 2) void fused_mfma(
        const bf16* __restrict__ packed,
        const bf16* __restrict__ wtb,
        const bf16* __restrict__ wtb2,
        const float* __restrict__ ob,
        const float* __restrict__ db,
        float* __restrict__ out) {
    __shared__ short wbuf[2][WTAP];           // 49152 B
    __shared__ float offl[64][20];            // 5120 B

    int tid = threadIdx.x;
    int L = tid & 63;
    int wv = tid >> 6;
    int px = L & 15;
    int lg = L >> 4;
    int blk = blockIdx.x;
    int region = (blk & 7) * 72 + (blk >> 3); // 576 blocks, XCD swizzle
    int p0 = region * 64;
    int b = p0 / HW;
    int pb = p0 - b * HW;
    int mypix = wv * 16 + px;
    int pid = pb + mypix;
    int x = pid % Wd, y = pid / Wd;
    const char* pkb = (const char*)packed + (size_t)b * HW * (C3 * 2);

    // ---- stage wtb2 (36 KB) into wbuf region ----
    {
        const s8v* src = (const s8v*)wtb2;
        s8v* dst = (s8v*)&wbuf[0][0];
#pragma unroll
        for (int i = 0; i < 9; ++i)
            dst[i * 256 + tid] = src[i * 256 + tid];
    }
    __syncthreads();

    // ================= phase 0: offset conv (16 px/wave, K=576) ===========
    {
        const s8v* A2 = (const s8v*)&wbuf[0][0];
        f4v oa0 = {0.f, 0.f, 0.f, 0.f};
        f4v oa1 = {0.f, 0.f, 0.f, 0.f};
#pragma unroll
        for (int t = 0; t < 9; ++t) {
            int yy = y - 1 + t / 3, xx = x - 1 + t % 3;
            bool val = (unsigned)yy < (unsigned)Hd && (unsigned)xx < (unsigned)Wd;
            int oc = ((val ? yy : 0) * Wd + (val ? xx : 0)) * (C3 * 2);
            short m = val ? (short)-1 : (short)0;
            s8v u0 = *(const s8v*)(pkb + oc + (0 * 4 + lg) * 16);
            s8v u1 = *(const s8v*)(pkb + oc + (1 * 4 + lg) * 16);
#pragma unroll
            for (int kc = 0; kc < 2; ++kc) {
                s8v bfrag = (kc ? u1 : u0) & m;
                s8v a0 = A2[((t * 2 + kc) * 2 + 0) * 64 + L];
                s8v a1 = A2[((t * 2 + kc) * 2 + 1) * 64 + L];
                oa0 = __builtin_amdgcn_mfma_f32_16x16x32_bf16(a0, bfrag, oa0, 0, 0, 0);
                oa1 = __builtin_amdgcn_mfma_f32_16x16x32_bf16(a1, bfrag, oa1, 0, 0, 0);
            }
        }
        // write offsets+bias to offl[mypix][v]  (D col = px, row = lg*4+r)
#pragma unroll
        for (int r = 0; r < 4; ++r)
            offl[wv * 16 + px][lg * 4 + r] = oa0[r] + ob[lg * 4 + r];
        if (lg == 0) {
#pragma unroll
            for (int r = 0; r < 2; ++r)
                offl[wv * 16 + px][16 + r] = oa1[r] + ob[16 + r];
        }
    }
    __syncthreads();   // offl complete; wbuf free for reuse

    // ---- stage deform tap 0 into wbuf[0] ----
    {
        const s8v* src = (const s8v*)wtb;
        s8v* dst = (s8v*)&wbuf[0][0];
#pragma unroll
        for (int i = 0; i < 6; ++i)
            dst[i * 256 + tid] = src[i * 256 + tid];
    }
    __syncthreads();

    // ================= phase 1: deform conv (16 px/wave, K=1728) ==========
    f4v acc[4];
    acc[0] = acc[1] = acc[2] = acc[3] = (f4v){0.f, 0.f, 0.f, 0.f};

#pragma unroll 1
    for (int t = 0; t < 9; ++t) {
        // issue next tap's staging loads (in flight during compute)
        s8v stg[6];
        if (t < 8) {
            const s8v* src = (const s8v*)wtb + (size_t)(t + 1) * (WTAP / 8);
#pragma unroll
            for (int i = 0; i < 6; ++i)
                stg[i] = src[i * 256 + tid];
        }

        // compute tap t
        float2 o2 = *(const float2*)&offl[mypix][2 * t];
        Ctx c = mkctx(t, y, x, o2);
        const short* W = &wbuf[t & 1][0];
#pragma unroll
        for (int kc = 0; kc < 6; ++kc) {
            int co = (kc * 4 + lg) * 16;
            s8v g0 = *(const s8v*)(pkb + c.o00 + co);
            s8v g1 = *(const s8v*)(pkb + c.o01 + co);
            s8v g2 = *(const s8v*)(pkb + c.o10 + co);
            s8v g3 = *(const s8v*)(pkb + c.o11 + co);
            u4v u00 = __builtin_bit_cast(u4v, g0);
            u4v u01 = __builtin_bit_cast(u4v, g1);
            u4v u10 = __builtin_bit_cast(u4v, g2);
            u4v u11 = __builtin_bit_cast(u4v, g3);
            u4v bu;
#pragma unroll
            for (int p = 0; p < 4; ++p) {
                float vlo = c.W00 * blo(u00[p]) + c.W01 * blo(u01[p])
                          + c.W10 * blo(u10[p]) + c.W11 * blo(u11[p]);
                float vhi = c.W00 * bhi(u00[p]) + c.W01 * bhi(u01[p])
                          + c.W10 * bhi(u10[p]) + c.W11 * bhi(u11[p]);
                bu[p] = packbf2(vlo, vhi);
            }
            s8v bfrag = __builtin_bit_cast(s8v, bu);
#pragma unroll
            for (int mt = 0; mt < 4; ++mt) {
                s8v a = *(const s8v*)(W + ((size_t)(kc * 4 + mt) * 64 + L) * 8);
                acc[mt] = __builtin_amdgcn_mfma_f32_16x16x32_bf16(a, bfrag, acc[mt], 0, 0, 0);
            }
        }

        // commit staged weights to the other buffer, then barrier
        if (t < 8) {
            s8v* dst = (s8v*)&wbuf[(t + 1) & 1][0];
#pragma unroll
            for (int i = 0; i < 6; ++i)
                dst[i * 256 + tid] = stg[i];
        }
        __syncthreads();
    }

    // epilogue: bias + ReLU; D col = px, row(o in tile) = lg*4+r
#pragma unroll
    for (int mt = 0; mt < 4; ++mt) {
#pragma unroll
        for (int r = 0; r < 4; ++r) {
            int o = mt * 16 + lg * 4 + r;
            out[((size_t)(b * On + o)) * HW + pb + mypix] =
                fmaxf(acc[mt][r] + db[o], 0.f);
        }
    }
}

// ---------------------------------------------------------------------------
extern "C" void kernel_launch(void* const* d_in, const int* in_sizes, int n_in,
                              void* d_out, int out_size, void* d_ws, size_t ws_size,
                              hipStream_t stream) {
    const float* ref  = (const float*)d_in[0];
    const float* dist = (const float*)d_in[1];
    const float* ow   = (const float*)d_in[2];
    const float* ob   = (const float*)d_in[3];
    const float* dw   = (const float*)d_in[4];
    const float* db   = (const float*)d_in[5];

    float* out = (float*)d_out;               // [feat | diff], each NFEAT f32

    // ws: wtb bf16 | wtb2 bf16 | packed bf16 [NPIX][192]
    bf16* ws_wtb  = (bf16*)d_ws;
    bf16* ws_wtb2 = ws_wtb + NWTB;
    bf16* ws_pk   = ws_wtb2 + NWTB2;

    repack_kernel<<<Bn * (HW / 64), 256, 0, stream>>>(
        ref, dist, (unsigned int*)ws_pk, out + NFEAT, dw, ow, ws_wtb, ws_wtb2);
    fused_mfma<<<NPIX / 64, 256, 0, stream>>>(
        ws_pk, ws_wtb, ws_wtb2, ob, db, out);
}